// Round 3
// baseline (86.595 us; speedup 1.0000x reference)
//
#include <hip/hip_runtime.h>

#define W_IN  4096
#define H_IN  4096
#define W_OUT 4090
#define H_OUT 4090
#define COLS  4              // output cols per thread
#define ROWS  7              // output rows per thread (ring = kernel height)
#define BX    64             // threads in x (one wave wide)
#define BY    4              // threads in y
#define NROWS (ROWS + 6)     // input rows streamed per thread

__global__ __launch_bounds__(256, 4) void conv7x7(
    const float* __restrict__ x, const float* __restrict__ wgt,
    const float* __restrict__ bias, float* __restrict__ out)
{
    const int tx  = threadIdx.x & (BX - 1);
    const int ty  = threadIdx.x >> 6;
    const int cx  = (blockIdx.x * BX + tx) * COLS;      // first output col
    const int ry0 = (blockIdx.y * BY + ty) * ROWS;      // first output row

    // weights + bias: uniform addresses -> scalar loads (SGPR-resident)
    float Wt[49];
    #pragma unroll
    for (int i = 0; i < 49; ++i) Wt[i] = wgt[i];
    const float bb = bias[0];

    // column-edge load guards (hoisted; only last x-block diverges)
    const bool ok1 = (cx + 7) < W_IN;   // second float4 in-bounds
    const bool ok2 = (cx + 9) < W_IN;   // trailing float2 in-bounds

    float acc[ROWS][COLS];
    #pragma unroll
    for (int i = 0; i < ROWS; ++i)
        #pragma unroll
        for (int c = 0; c < COLS; ++c) acc[i][c] = 0.f;

    #pragma unroll
    for (int r = 0; r < NROWS; ++r) {
        const int gy = ry0 + r;
        float f[10];                     // sliding window: COLS + 6 floats
        if (gy < H_IN) {
            const float* row = x + (size_t)gy * W_IN + cx;   // 16B-aligned
            const float4 s0 = *reinterpret_cast<const float4*>(row);
            float4 s1 = make_float4(0.f, 0.f, 0.f, 0.f);
            float2 s2 = make_float2(0.f, 0.f);
            if (ok1) s1 = *reinterpret_cast<const float4*>(row + 4);
            if (ok2) s2 = *reinterpret_cast<const float2*>(row + 8);
            f[0] = s0.x; f[1] = s0.y; f[2] = s0.z; f[3] = s0.w;
            f[4] = s1.x; f[5] = s1.y; f[6] = s1.z; f[7] = s1.w;
            f[8] = s2.x; f[9] = s2.y;
        } else {
            #pragma unroll
            for (int i = 0; i < 10; ++i) f[i] = 0.f;
        }

        // accumulate this input row into every output row it touches (static)
        #pragma unroll
        for (int ky = 0; ky < 7; ++ky) {
            const int oy = r - ky;                    // static
            if (oy >= 0 && oy < ROWS) {               // static predicate
                #pragma unroll
                for (int kx = 0; kx < 7; ++kx) {
                    const float w = Wt[ky * 7 + kx];
                    #pragma unroll
                    for (int c = 0; c < COLS; ++c)
                        acc[oy][c] += w * f[kx + c];
                }
            }
        }

        // input row r completes output row r-6
        const int oy = r - 6;                         // static
        if (oy >= 0) {
            const int gyo = ry0 + oy;
            if (gyo < H_OUT) {
                float* po = out + (size_t)gyo * W_OUT + cx;
                if (cx + COLS <= W_OUT) {
                    // out row stride 4090 (even) & cx even -> 8B-aligned
                    float2 o01 = make_float2(acc[oy][0] + bb, acc[oy][1] + bb);
                    float2 o23 = make_float2(acc[oy][2] + bb, acc[oy][3] + bb);
                    *reinterpret_cast<float2*>(po)     = o01;
                    *reinterpret_cast<float2*>(po + 2) = o23;
                } else {
                    #pragma unroll
                    for (int c = 0; c < COLS; ++c)
                        if (cx + c < W_OUT) po[c] = acc[oy][c] + bb;
                }
            }
        }
    }
}

extern "C" void kernel_launch(void* const* d_in, const int* in_sizes, int n_in,
                              void* d_out, int out_size, void* d_ws, size_t ws_size,
                              hipStream_t stream) {
    const float* x = (const float*)d_in[0];
    const float* w = (const float*)d_in[1];
    const float* b = (const float*)d_in[2];
    float* out = (float*)d_out;
    // x: ceil(4090 / (64*4)) = 16 ; y: ceil(ceil(4090/7)=585 / 4) = 147
    dim3 grid(16, 147);
    conv7x7<<<grid, 256, 0, stream>>>(x, w, b, out);
}